// Round 1
// 744.114 us; speedup vs baseline: 1.0827x; 1.0827x over previous
//
#include <hip/hip_runtime.h>

#define T_STEPS 64
#define INPUT_BITS 1024
#define N_STATE 2048
#define N_OUT 256
#define NB 16
#define HASHROW 65536
#define NBLK 32

// ws layout:
//   u64[0..64)      state buf0: tagged words {hi32 = step tag, lo32 = 32 state bits}
//   u64[64..128)    state buf1
//   u32[256..2304)  packed input windows (65536 bits)
// No barrier counter: data and flag travel together in one atomic u64.
#define WS_PK 256
#define WS_WORDS_NEEDED 2304

// ---------------- init: pack input bits, zero tagged state bufs ----------------
__global__ __launch_bounds__(256) void ram_init_kernel(
    const int* __restrict__ input_bits, unsigned int* __restrict__ ws)
{
    const int tid = threadIdx.x, lane = tid & 63;
    const int gw = blockIdx.x * 4 + (tid >> 6);      // global wave 0..127
#pragma unroll
    for (int i = 0; i < 8; i++) {
        int g = gw * 8 + i;                           // bit-group 0..1023
        int v = input_bits[g * 64 + lane];
        unsigned long long m = __ballot(v != 0);
        if (lane == 0) {
            ws[WS_PK + 2 * g]     = (unsigned int)(m & 0xFFFFFFFFull);
            ws[WS_PK + 2 * g + 1] = (unsigned int)(m >> 32);
        }
    }
    if (blockIdx.x == 0 && tid < 256) ws[tid] = 0u;   // tag=0 in both state bufs
}

// ---------------- main: 32 blocks x 1 wave, tagged-word distributed sync ----------------
__global__ __launch_bounds__(64) void ram_main_kernel(
    const int* __restrict__ conn_state,      // [2048*16] in [0,3072)
    const int* __restrict__ conn_out,        // [256*16]  in [0,2048)
    const float* __restrict__ state_table,   // [2048*65536]
    const float* __restrict__ output_table,  // [256*65536]
    unsigned int* __restrict__ ws,
    float* __restrict__ out)                 // [256]
{
    __shared__ unsigned int pk[2048];  // all packed windows
    __shared__ unsigned int xw[96];    // concat vector: [0,32) window, [32,96) state

    const int lane = threadIdx.x;
    const int b = blockIdx.x;

    // stage packed windows ws -> LDS (one-time, off critical path)
    for (int i = lane; i < 2048; i += 64) pk[i] = ws[WS_PK + i];

    // this block's 64 neurons
    const unsigned int neuron = (unsigned int)(b * 64 + lane);
    int cn[NB];
#pragma unroll
    for (int j = 0; j < NB; j++) cn[j] = conn_state[neuron * NB + j];
    const float* row = state_table + (size_t)neuron * HASHROW;

    // prefetch output connectivity off the critical path (blocks 0..3 only)
    int co[NB];
    if (b < 4) {
#pragma unroll
        for (int j = 0; j < NB; j++) co[j] = conn_out[(b * 64 + lane) * NB + j];
    }

    xw[32 + lane] = 0u;                   // S_0 = 0
    if (lane < 32) xw[lane] = pk[lane];   // W_0
    __syncthreads();                      // single wave: cheap, one-time

    unsigned long long* const sbuf = (unsigned long long*)ws;

    for (int t = 0; t < T_STEPS; t++) {
        // addresses from (window, state)
        unsigned int a = 0;
#pragma unroll
        for (int j = 0; j < NB; j++)
            a |= ((xw[cn[j] >> 5] >> (cn[j] & 31)) & 1u) << j;
        float v = row[a];                              // random cold HBM line
        unsigned long long m = __ballot(v > 0.5f);     // 64 new state bits, wave-uniform

        const unsigned int tag = (unsigned int)(t + 1);
        unsigned long long* const bw = sbuf + (size_t)((t + 1) & 1) * 64;

        // publish: one tagged u64 per 32-bit state half (atomic => tag+data consistent)
        if (lane < 2) {
            unsigned int half = (lane == 0) ? (unsigned int)(m & 0xFFFFFFFFull)
                                            : (unsigned int)(m >> 32);
            __hip_atomic_store(&bw[2 * b + lane],
                               ((unsigned long long)tag << 32) | (unsigned long long)half,
                               __ATOMIC_RELAXED, __HIP_MEMORY_SCOPE_AGENT);
        }

        // next window into LDS while stores/polls are in flight
        if (t < T_STEPS - 1 && lane < 32) xw[lane] = pk[(t + 1) * 32 + lane];

        // distributed poll: lane i owns tagged word i; predicated off once matched
        unsigned long long vv = 0;
        bool done = false;
        for (;;) {
            if (!done) {
                vv = __hip_atomic_load(&bw[lane], __ATOMIC_RELAXED,
                                       __HIP_MEMORY_SCOPE_AGENT);
                done = ((unsigned int)(vv >> 32) == tag);
            }
            if (__all(done)) break;
        }
        xw[32 + lane] = (unsigned int)(vv & 0xFFFFFFFFull);  // S_{t+1}
    }

    // output layer: blocks 0..3, one output neuron per lane
    if (b < 4) {
        unsigned int a = 0;
#pragma unroll
        for (int j = 0; j < NB; j++)
            a |= ((xw[32 + (co[j] >> 5)] >> (co[j] & 31)) & 1u) << j;
        out[b * 64 + lane] = output_table[(size_t)(b * 64 + lane) * HASHROW + a];
    }
}

// ---------------- fallback: round-1 single-block kernel (if ws too small) ----------------
__global__ __launch_bounds__(1024) void ram_seq_kernel(
    const int* __restrict__ input_bits, const int* __restrict__ conn_state,
    const int* __restrict__ conn_out, const float* __restrict__ state_table,
    const float* __restrict__ output_table, float* __restrict__ out)
{
    __shared__ unsigned int pk[2048];
    __shared__ unsigned int xw[96];
    const int tid = threadIdx.x, lane = tid & 63, wave = tid >> 6;

    for (int g = wave; g < 1024; g += 16) {
        int v = input_bits[g * 64 + lane];
        unsigned long long m = __ballot(v != 0);
        if (lane == 0) {
            pk[2 * g] = (unsigned int)(m & 0xFFFFFFFFull);
            pk[2 * g + 1] = (unsigned int)(m >> 32);
        }
    }
    if (tid < 64) xw[32 + tid] = 0u;
    int c0[NB], c1[NB];
#pragma unroll
    for (int j = 0; j < NB; j++) {
        c0[j] = conn_state[tid * NB + j];
        c1[j] = conn_state[(tid + 1024) * NB + j];
    }
    const float* row0 = state_table + (size_t)tid * HASHROW;
    const float* row1 = state_table + (size_t)(tid + 1024) * HASHROW;
    __syncthreads();
    if (tid < 32) xw[tid] = pk[tid];
    __syncthreads();
    for (int t = 0; t < T_STEPS; t++) {
        unsigned int a0 = 0, a1 = 0;
#pragma unroll
        for (int j = 0; j < NB; j++) {
            a0 |= ((xw[c0[j] >> 5] >> (c0[j] & 31)) & 1u) << j;
            a1 |= ((xw[c1[j] >> 5] >> (c1[j] & 31)) & 1u) << j;
        }
        float v0 = row0[a0], v1 = row1[a1];
        __syncthreads();
        unsigned long long m0 = __ballot(v0 > 0.5f);
        unsigned long long m1 = __ballot(v1 > 0.5f);
        if (lane == 0) {
            xw[32 + 2 * wave] = (unsigned int)(m0 & 0xFFFFFFFFull);
            xw[32 + 2 * wave + 1] = (unsigned int)(m0 >> 32);
            xw[64 + 2 * wave] = (unsigned int)(m1 & 0xFFFFFFFFull);
            xw[64 + 2 * wave + 1] = (unsigned int)(m1 >> 32);
        }
        if (t < T_STEPS - 1 && tid < 32) xw[tid] = pk[(t + 1) * 32 + tid];
        __syncthreads();
    }
    if (tid < N_OUT) {
        unsigned int a = 0;
#pragma unroll
        for (int j = 0; j < NB; j++) {
            int c = conn_out[tid * NB + j];
            a |= ((xw[32 + (c >> 5)] >> (c & 31)) & 1u) << j;
        }
        out[tid] = output_table[(size_t)tid * HASHROW + a];
    }
}

extern "C" void kernel_launch(void* const* d_in, const int* in_sizes, int n_in,
                              void* d_out, int out_size, void* d_ws, size_t ws_size,
                              hipStream_t stream) {
    const int*   input_bits   = (const int*)d_in[0];
    const int*   conn_state   = (const int*)d_in[1];
    const int*   conn_out     = (const int*)d_in[2];
    const float* state_table  = (const float*)d_in[3];
    const float* output_table = (const float*)d_in[4];
    float*       out          = (float*)d_out;

    if (ws_size >= WS_WORDS_NEEDED * sizeof(unsigned int)) {
        unsigned int* ws = (unsigned int*)d_ws;
        ram_init_kernel<<<NBLK, 256, 0, stream>>>(input_bits, ws);
        ram_main_kernel<<<NBLK, 64, 0, stream>>>(conn_state, conn_out, state_table,
                                                 output_table, ws, out);
    } else {
        ram_seq_kernel<<<1, 1024, 0, stream>>>(input_bits, conn_state, conn_out,
                                               state_table, output_table, out);
    }
}

// Round 2
// 741.898 us; speedup vs baseline: 1.0859x; 1.0030x over previous
//
#include <hip/hip_runtime.h>

#define T_STEPS 64
#define INPUT_BITS 1024
#define N_STATE 2048
#define N_OUT 256
#define NB 16
#define HASHROW 65536
#define NBLK 32

// ws layout:
//   u64[0..64)      state buf0: tagged words {hi32 = step tag, lo32 = 32 state bits}
//   u64[64..128)    state buf1
//   u32[256..2304)  packed input windows (65536 bits)
// No barrier counter: data and flag travel together in one atomic u64.
#define WS_PK 256
#define WS_WORDS_NEEDED 2304

// ---------------- init: pack input bits, zero tagged state bufs ----------------
__global__ __launch_bounds__(256) void ram_init_kernel(
    const int* __restrict__ input_bits, unsigned int* __restrict__ ws)
{
    const int tid = threadIdx.x, lane = tid & 63;
    const int gw = blockIdx.x * 4 + (tid >> 6);      // global wave 0..127
#pragma unroll
    for (int i = 0; i < 8; i++) {
        int g = gw * 8 + i;                           // bit-group 0..1023
        int v = input_bits[g * 64 + lane];
        unsigned long long m = __ballot(v != 0);
        if (lane == 0) {
            ws[WS_PK + 2 * g]     = (unsigned int)(m & 0xFFFFFFFFull);
            ws[WS_PK + 2 * g + 1] = (unsigned int)(m >> 32);
        }
    }
    if (blockIdx.x == 0 && tid < 256) ws[tid] = 0u;   // tag=0 in both state bufs
}

// ---------------- main: 32 blocks x 1 wave, tagged-word distributed sync ----------------
__global__ __launch_bounds__(64) void ram_main_kernel(
    const int* __restrict__ conn_state,      // [2048*16] in [0,3072)
    const int* __restrict__ conn_out,        // [256*16]  in [0,2048)
    const float* __restrict__ state_table,   // [2048*65536]
    const float* __restrict__ output_table,  // [256*65536]
    unsigned int* __restrict__ ws,
    float* __restrict__ out)                 // [256]
{
    __shared__ unsigned int pk[2048];  // all packed windows
    __shared__ unsigned int xw[96];    // concat vector: [0,32) window, [32,96) state

    const int lane = threadIdx.x;
    const int b = blockIdx.x;

    // stage packed windows ws -> LDS (one-time, off critical path)
    for (int i = lane; i < 2048; i += 64) pk[i] = ws[WS_PK + i];

    // this block's 64 neurons
    const unsigned int neuron = (unsigned int)(b * 64 + lane);
    int cn[NB];
#pragma unroll
    for (int j = 0; j < NB; j++) cn[j] = conn_state[neuron * NB + j];
    const float* row = state_table + (size_t)neuron * HASHROW;

    // prefetch output connectivity off the critical path (blocks 0..3 only)
    int co[NB];
    if (b < 4) {
#pragma unroll
        for (int j = 0; j < NB; j++) co[j] = conn_out[(b * 64 + lane) * NB + j];
    }

    xw[32 + lane] = 0u;                   // S_0 = 0
    if (lane < 32) xw[lane] = pk[lane];   // W_0
    __syncthreads();                      // single wave: cheap, one-time

    unsigned long long* const sbuf = (unsigned long long*)ws;

    for (int t = 0; t < T_STEPS; t++) {
        // addresses from (window, state)
        unsigned int a = 0;
#pragma unroll
        for (int j = 0; j < NB; j++)
            a |= ((xw[cn[j] >> 5] >> (cn[j] & 31)) & 1u) << j;
        float v = row[a];                              // random cold HBM line
        unsigned long long m = __ballot(v > 0.5f);     // 64 new state bits, wave-uniform

        const unsigned int tag = (unsigned int)(t + 1);
        unsigned long long* const bw = sbuf + (size_t)((t + 1) & 1) * 64;

        // publish: one tagged u64 per 32-bit state half (atomic => tag+data consistent)
        if (lane < 2) {
            unsigned int half = (lane == 0) ? (unsigned int)(m & 0xFFFFFFFFull)
                                            : (unsigned int)(m >> 32);
            __hip_atomic_store(&bw[2 * b + lane],
                               ((unsigned long long)tag << 32) | (unsigned long long)half,
                               __ATOMIC_RELAXED, __HIP_MEMORY_SCOPE_AGENT);
        }

        // publishers that never consume the final state exit after the last store
        if (t == T_STEPS - 1 && b >= 4) break;

        // next window into LDS while stores/polls are in flight
        if (t < T_STEPS - 1 && lane < 32) xw[lane] = pk[(t + 1) * 32 + lane];

        // distributed poll, 2-deep pipelined: lane i owns tagged word i;
        // two independent loads stay in flight so the sampling period ~halves.
        unsigned long long vv = 0;
        bool done = false;
        unsigned long long p0 = __hip_atomic_load(&bw[lane], __ATOMIC_RELAXED,
                                                  __HIP_MEMORY_SCOPE_AGENT);
        unsigned long long p1 = __hip_atomic_load(&bw[lane], __ATOMIC_RELAXED,
                                                  __HIP_MEMORY_SCOPE_AGENT);
        for (;;) {
            if (!done && (unsigned int)(p0 >> 32) == tag) { vv = p0; done = true; }
            if (__all(done)) break;
            if (!done) p0 = __hip_atomic_load(&bw[lane], __ATOMIC_RELAXED,
                                              __HIP_MEMORY_SCOPE_AGENT);
            if (!done && (unsigned int)(p1 >> 32) == tag) { vv = p1; done = true; }
            if (__all(done)) break;
            if (!done) p1 = __hip_atomic_load(&bw[lane], __ATOMIC_RELAXED,
                                              __HIP_MEMORY_SCOPE_AGENT);
        }
        xw[32 + lane] = (unsigned int)(vv & 0xFFFFFFFFull);  // S_{t+1}
    }

    // output layer: blocks 0..3, one output neuron per lane
    if (b < 4) {
        unsigned int a = 0;
#pragma unroll
        for (int j = 0; j < NB; j++)
            a |= ((xw[32 + (co[j] >> 5)] >> (co[j] & 31)) & 1u) << j;
        out[b * 64 + lane] = output_table[(size_t)(b * 64 + lane) * HASHROW + a];
    }
}

// ---------------- fallback: round-1 single-block kernel (if ws too small) ----------------
__global__ __launch_bounds__(1024) void ram_seq_kernel(
    const int* __restrict__ input_bits, const int* __restrict__ conn_state,
    const int* __restrict__ conn_out, const float* __restrict__ state_table,
    const float* __restrict__ output_table, float* __restrict__ out)
{
    __shared__ unsigned int pk[2048];
    __shared__ unsigned int xw[96];
    const int tid = threadIdx.x, lane = tid & 63, wave = tid >> 6;

    for (int g = wave; g < 1024; g += 16) {
        int v = input_bits[g * 64 + lane];
        unsigned long long m = __ballot(v != 0);
        if (lane == 0) {
            pk[2 * g] = (unsigned int)(m & 0xFFFFFFFFull);
            pk[2 * g + 1] = (unsigned int)(m >> 32);
        }
    }
    if (tid < 64) xw[32 + tid] = 0u;
    int c0[NB], c1[NB];
#pragma unroll
    for (int j = 0; j < NB; j++) {
        c0[j] = conn_state[tid * NB + j];
        c1[j] = conn_state[(tid + 1024) * NB + j];
    }
    const float* row0 = state_table + (size_t)tid * HASHROW;
    const float* row1 = state_table + (size_t)(tid + 1024) * HASHROW;
    __syncthreads();
    if (tid < 32) xw[tid] = pk[tid];
    __syncthreads();
    for (int t = 0; t < T_STEPS; t++) {
        unsigned int a0 = 0, a1 = 0;
#pragma unroll
        for (int j = 0; j < NB; j++) {
            a0 |= ((xw[c0[j] >> 5] >> (c0[j] & 31)) & 1u) << j;
            a1 |= ((xw[c1[j] >> 5] >> (c1[j] & 31)) & 1u) << j;
        }
        float v0 = row0[a0], v1 = row1[a1];
        __syncthreads();
        unsigned long long m0 = __ballot(v0 > 0.5f);
        unsigned long long m1 = __ballot(v1 > 0.5f);
        if (lane == 0) {
            xw[32 + 2 * wave] = (unsigned int)(m0 & 0xFFFFFFFFull);
            xw[32 + 2 * wave + 1] = (unsigned int)(m0 >> 32);
            xw[64 + 2 * wave] = (unsigned int)(m1 & 0xFFFFFFFFull);
            xw[64 + 2 * wave + 1] = (unsigned int)(m1 >> 32);
        }
        if (t < T_STEPS - 1 && tid < 32) xw[tid] = pk[(t + 1) * 32 + tid];
        __syncthreads();
    }
    if (tid < N_OUT) {
        unsigned int a = 0;
#pragma unroll
        for (int j = 0; j < NB; j++) {
            int c = conn_out[tid * NB + j];
            a |= ((xw[32 + (c >> 5)] >> (c & 31)) & 1u) << j;
        }
        out[tid] = output_table[(size_t)tid * HASHROW + a];
    }
}

extern "C" void kernel_launch(void* const* d_in, const int* in_sizes, int n_in,
                              void* d_out, int out_size, void* d_ws, size_t ws_size,
                              hipStream_t stream) {
    const int*   input_bits   = (const int*)d_in[0];
    const int*   conn_state   = (const int*)d_in[1];
    const int*   conn_out     = (const int*)d_in[2];
    const float* state_table  = (const float*)d_in[3];
    const float* output_table = (const float*)d_in[4];
    float*       out          = (float*)d_out;

    if (ws_size >= WS_WORDS_NEEDED * sizeof(unsigned int)) {
        unsigned int* ws = (unsigned int*)d_ws;
        ram_init_kernel<<<NBLK, 256, 0, stream>>>(input_bits, ws);
        ram_main_kernel<<<NBLK, 64, 0, stream>>>(conn_state, conn_out, state_table,
                                                 output_table, ws, out);
    } else {
        ram_seq_kernel<<<1, 1024, 0, stream>>>(input_bits, conn_state, conn_out,
                                               state_table, output_table, out);
    }
}